// Round 1
// baseline (782.912 us; speedup 1.0000x reference)
//
#include <hip/hip_runtime.h>

// Problem constants (fixed by reference): L=2048, B=32, D=512
#define LL 2048
#define BB 32
#define DD 512
#define MM (LL * BB)   /* 65536 GEMM rows  */
#define NN (3 * DD)    /* 1536  GEMM cols  */
#define KK (DD)        /* 512   GEMM depth */

typedef short bf16x8 __attribute__((ext_vector_type(8)));
typedef float f32x4 __attribute__((ext_vector_type(4)));

__device__ __forceinline__ unsigned short f2bf(float f) {
  unsigned u = __builtin_bit_cast(unsigned, f);
  u += 0x7fffu + ((u >> 16) & 1u);   // round-to-nearest-even
  return (unsigned short)(u >> 16);
}
__device__ __forceinline__ float bf2f(unsigned short h) {
  unsigned u = (unsigned)h << 16;
  return __builtin_bit_cast(float, u);
}
__device__ __forceinline__ float fsigmoid(float t) {
  // 1/(1+exp(-t)) = 1/(1 + 2^(-t*log2 e)); v_exp_f32 + v_rcp_f32
  float e = __builtin_amdgcn_exp2f(t * -1.442695040888963f);
  return __builtin_amdgcn_rcpf(1.0f + e);
}
// async global->LDS, 16B/lane; LDS dest = wave-uniform base + lane*16
__device__ __forceinline__ void lds_cp16(unsigned short* lds, const unsigned short* g) {
  __builtin_amdgcn_global_load_lds(
      (const __attribute__((address_space(1))) void*)g,
      (__attribute__((address_space(3))) void*)lds, 16, 0, 0);
}

// ---------------- kernel 1: x (fp32) -> xb (bf16), 4 elems/thread ----------
__global__ __launch_bounds__(256) void cvt_x_kernel(const float* __restrict__ x,
                                                    unsigned short* __restrict__ xb) {
  int i = blockIdx.x * 256 + threadIdx.x;      // 8388608 threads, exact
  float4 v = ((const float4*)x)[i];
  ushort4 o;
  o.x = f2bf(v.x); o.y = f2bf(v.y); o.z = f2bf(v.z); o.w = f2bf(v.w);
  ((ushort4*)xb)[i] = o;
}

// ------- kernel 2: W (D x 3D fp32) -> WrT (bf16, [o'=g*D+d][k] N-major) ----
// WrT[o'][i] = W[i][3*d + g]  with o' = g*512 + d. Tiny (3 MB read).
__global__ __launch_bounds__(256) void cvt_w_kernel(const float* __restrict__ W,
                                                    unsigned short* __restrict__ Wt) {
  int j = blockIdx.x * 256 + threadIdx.x;      // 786432 threads, exact
  int i  = j & (KK - 1);                       // k index 0..511
  int op = j >> 9;                             // o' 0..1535
  int g  = op >> 9;                            // gate 0..2
  int dd = op & (DD - 1);                      // d 0..511
  Wt[j] = f2bf(W[(size_t)i * NN + dd * 3 + g]);
}

// ---------------- kernel 3: GEMM  U[M][N] (bf16) = xb[M][K] * WrT^T --------
// m97 structure: 128x128 tile, BK=32, 4 waves, 16 MFMA 16x16x32 each.
__global__ __launch_bounds__(256) void gemm_kernel(const unsigned short* __restrict__ A,
                                                   const unsigned short* __restrict__ Bt,
                                                   unsigned short* __restrict__ U) {
  __shared__ __align__(16) unsigned short sA[128 * 32];
  __shared__ __align__(16) unsigned short sB[128 * 32];
  const int tn = blockIdx.x * 128;             // N tile (12 tiles)
  const int tm = blockIdx.y * 128;             // M tile (512 tiles)
  const int lane = threadIdx.x & 63;
  const int wv   = threadIdx.x >> 6;
  const int wm = (wv & 1) * 64;                // wave quadrant
  const int wn = (wv >> 1) * 64;
  const int quad = lane >> 4;                  // 0..3
  const int l16  = lane & 15;

  f32x4 acc[4][4] = {};

  const int srow = lane >> 2;                  // staging row within 16-row seg
  const int scol = (lane & 3) * 8;             // staging col (bf16 elems)

  for (int k0 = 0; k0 < KK; k0 += 32) {
#pragma unroll
    for (int t = 0; t < 2; ++t) {
      int seg = wv * 2 + t;                    // 0..7, wave-uniform
      int row = seg * 16 + srow;
      lds_cp16(&sA[seg * 512], &A [(size_t)(tm + row) * KK + k0 + scol]);
      lds_cp16(&sB[seg * 512], &Bt[(size_t)(tn + row) * KK + k0 + scol]);
    }
    __syncthreads();                           // compiler drains vmcnt here

    bf16x8 af[4], bf[4];
#pragma unroll
    for (int i = 0; i < 4; ++i) {
      af[i] = *(const bf16x8*)&sA[(wm + i * 16 + l16) * 32 + quad * 8];
      bf[i] = *(const bf16x8*)&sB[(wn + i * 16 + l16) * 32 + quad * 8];
    }
#pragma unroll
    for (int i = 0; i < 4; ++i)
#pragma unroll
      for (int j = 0; j < 4; ++j)
        acc[i][j] = __builtin_amdgcn_mfma_f32_16x16x32_bf16(af[i], bf[j], acc[i][j], 0, 0, 0);
    __syncthreads();
  }

  // epilogue: C/D layout col=lane&15, row=quad*4+reg
#pragma unroll
  for (int i = 0; i < 4; ++i)
#pragma unroll
    for (int j = 0; j < 4; ++j)
#pragma unroll
      for (int r = 0; r < 4; ++r) {
        int row = tm + wm + i * 16 + quad * 4 + r;
        int col = tn + wn + j * 16 + l16;
        U[(size_t)row * NN + col] = f2bf(acc[i][j][r]);
      }
}

// ---------------- kernel 4: sequential scan over L ------------------------
// One thread per (b,d); 256 blocks x 64 thr = 1 wave/CU. Register
// prefetch: 4 buffers x 8 steps, distance 2 (~64 outstanding loads/wave).
#define CH 8

__global__ __launch_bounds__(64, 1) void scan_kernel(const unsigned short* __restrict__ U,
                                                     const unsigned short* __restrict__ xb,
                                                     const float* __restrict__ wc,
                                                     const float* __restrict__ bias,
                                                     float* __restrict__ out) {
  int tid = blockIdx.x * 64 + threadIdx.x;     // 0..16383
  int d = tid & (DD - 1);
  int b = tid >> 9;
  const float wcf = wc[d],      wcr = wc[DD + d];
  const float bfv = bias[d],    brv = bias[DD + d];
  const unsigned short* Up = U  + (size_t)b * NN + d;   // +l*BB*NN per step
  const unsigned short* Xp = xb + (size_t)b * DD + d;   // +l*BB*DD per step
  float* hp = out + (size_t)b * DD + d;

  unsigned short B0[4][CH], B1[4][CH], B2[4][CH], BX[4][CH];

#define FETCH(l0, s)                                                      \
  do {                                                                    \
    _Pragma("unroll") for (int j = 0; j < CH; ++j) {                      \
      size_t uo = (size_t)((l0) + j) * (BB * NN);                         \
      B0[s][j] = Up[uo];                                                  \
      B1[s][j] = Up[uo + DD];                                             \
      B2[s][j] = Up[uo + 2 * DD];                                         \
      BX[s][j] = Xp[(size_t)((l0) + j) * (BB * DD)];                      \
    }                                                                     \
  } while (0)

#define COMP(l0, s)                                                       \
  do {                                                                    \
    _Pragma("unroll") for (int j = 0; j < CH; ++j) {                      \
      float u0 = bf2f(B0[s][j]);                                          \
      float u1 = bf2f(B1[s][j]);                                          \
      float u2 = bf2f(B2[s][j]);                                          \
      float xr = bf2f(BX[s][j]);                                          \
      float fg = fsigmoid(u1 + wcf * c + bfv);                            \
      float rg = fsigmoid(u2 + wcr * c + brv);                            \
      c = fg * (c - u0) + u0;                                             \
      hp[(size_t)((l0) + j) * (BB * DD)] = rg * (c - xr) + xr;            \
    }                                                                     \
  } while (0)

  float c = 0.0f;
  FETCH(0, 0);
  FETCH(CH, 1);
  for (int lo = 0; lo < LL; lo += 4 * CH) {
    /* guards only needed near the end; conditions are wave-uniform */
    if (lo + 2 * CH < LL) FETCH(lo + 2 * CH, 2);
    COMP(lo, 0);
    if (lo + 3 * CH < LL) FETCH(lo + 3 * CH, 3);
    COMP(lo + CH, 1);
    if (lo + 4 * CH < LL) FETCH(lo + 4 * CH, 0);
    COMP(lo + 2 * CH, 2);
    if (lo + 5 * CH < LL) FETCH(lo + 5 * CH, 1);
    COMP(lo + 3 * CH, 3);
  }
  // c_last, concatenated after h
  out[(size_t)LL * BB * DD + (size_t)b * DD + d] = c;
#undef FETCH
#undef COMP
}

extern "C" void kernel_launch(void* const* d_in, const int* in_sizes, int n_in,
                              void* d_out, int out_size, void* d_ws, size_t ws_size,
                              hipStream_t stream) {
  const float* x    = (const float*)d_in[0];   // (L,B,D) fp32
  const float* W    = (const float*)d_in[1];   // (D,3D) fp32
  const float* wc   = (const float*)d_in[2];   // (2D,)  fp32
  const float* bias = (const float*)d_in[3];   // (2D,)  fp32
  float* out = (float*)d_out;                  // h (L,B,D) fp32 ++ c_last (B,D)

  // workspace layout (bf16): xb 64MB | WrT 1.5MB | U 192MB  (total ~258MB)
  unsigned short* xb = (unsigned short*)d_ws;
  unsigned short* Wt = xb + (size_t)MM * KK;        // 33554432 elems
  unsigned short* U  = Wt + (size_t)NN * KK;        // 786432 elems

  cvt_x_kernel<<<(MM * KK) / (4 * 256), 256, 0, stream>>>(x, xb);
  cvt_w_kernel<<<(NN * KK) / 256, 256, 0, stream>>>(W, Wt);
  gemm_kernel<<<dim3(NN / 128, MM / 128), 256, 0, stream>>>(xb, Wt, U);
  scan_kernel<<<(BB * DD) / 64, 64, 0, stream>>>(U, xb, wc, bias, out);
}

// Round 2
// 471.215 us; speedup vs baseline: 1.6615x; 1.6615x over previous
//
#include <hip/hip_runtime.h>

// Problem constants (fixed by reference): L=2048, B=32, D=512
#define LL 2048
#define BB 32
#define DD 512
#define MM (LL * BB)   /* 65536 GEMM rows  */
#define NN (3 * DD)    /* 1536  GEMM cols  */
#define KK (DD)        /* 512   GEMM depth */

typedef short bf16x8 __attribute__((ext_vector_type(8)));
typedef float f32x4 __attribute__((ext_vector_type(4)));

__device__ __forceinline__ unsigned short f2bf(float f) {
  unsigned u = __builtin_bit_cast(unsigned, f);
  u += 0x7fffu + ((u >> 16) & 1u);   // round-to-nearest-even
  return (unsigned short)(u >> 16);
}
__device__ __forceinline__ float bf2f(unsigned short h) {
  unsigned u = (unsigned)h << 16;
  return __builtin_bit_cast(float, u);
}
// async global->LDS, 16B/lane; LDS dest = wave-uniform base + lane*16
__device__ __forceinline__ void lds_cp16(unsigned short* lds, const unsigned short* g) {
  __builtin_amdgcn_global_load_lds(
      (const __attribute__((address_space(1))) void*)g,
      (__attribute__((address_space(3))) void*)lds, 16, 0, 0);
}

// ---------------- kernel 1: x (fp32) -> xb (bf16), 4 elems/thread ----------
__global__ __launch_bounds__(256) void cvt_x_kernel(const float* __restrict__ x,
                                                    unsigned short* __restrict__ xb) {
  int i = blockIdx.x * 256 + threadIdx.x;      // 8388608 threads, exact
  float4 v = ((const float4*)x)[i];
  ushort4 o;
  o.x = f2bf(v.x); o.y = f2bf(v.y); o.z = f2bf(v.z); o.w = f2bf(v.w);
  ((ushort4*)xb)[i] = o;
}

// ------- kernel 2: W (D x 3D fp32) -> WrT (bf16, [o'=g*D+d][k] N-major) ----
__global__ __launch_bounds__(256) void cvt_w_kernel(const float* __restrict__ W,
                                                    unsigned short* __restrict__ Wt) {
  int j = blockIdx.x * 256 + threadIdx.x;      // 786432 threads, exact
  int i  = j & (KK - 1);                       // k index 0..511
  int op = j >> 9;                             // o' 0..1535
  int g  = op >> 9;                            // gate 0..2
  int dd = op & (DD - 1);                      // d 0..511
  Wt[j] = f2bf(W[(size_t)i * NN + dd * 3 + g]);
}

// ---------------- kernel 3: GEMM  U[M][N] (bf16) = xb[M][K] * WrT^T --------
// m97 structure: 128x128 tile, BK=32, 4 waves, 16 MFMA 16x16x32 each.
__global__ __launch_bounds__(256) void gemm_kernel(const unsigned short* __restrict__ A,
                                                   const unsigned short* __restrict__ Bt,
                                                   unsigned short* __restrict__ U) {
  __shared__ __align__(16) unsigned short sA[128 * 32];
  __shared__ __align__(16) unsigned short sB[128 * 32];
  const int tn = blockIdx.x * 128;             // N tile (12 tiles)
  const int tm = blockIdx.y * 128;             // M tile (512 tiles)
  const int lane = threadIdx.x & 63;
  const int wv   = threadIdx.x >> 6;
  const int wm = (wv & 1) * 64;                // wave quadrant
  const int wn = (wv >> 1) * 64;
  const int quad = lane >> 4;                  // 0..3
  const int l16  = lane & 15;

  f32x4 acc[4][4] = {};

  const int srow = lane >> 2;                  // staging row within 16-row seg
  const int scol = (lane & 3) * 8;             // staging col (bf16 elems)

  for (int k0 = 0; k0 < KK; k0 += 32) {
#pragma unroll
    for (int t = 0; t < 2; ++t) {
      int seg = wv * 2 + t;                    // 0..7, wave-uniform
      int row = seg * 16 + srow;
      lds_cp16(&sA[seg * 512], &A [(size_t)(tm + row) * KK + k0 + scol]);
      lds_cp16(&sB[seg * 512], &Bt[(size_t)(tn + row) * KK + k0 + scol]);
    }
    __syncthreads();                           // compiler drains vmcnt here

    bf16x8 af[4], bf[4];
#pragma unroll
    for (int i = 0; i < 4; ++i) {
      af[i] = *(const bf16x8*)&sA[(wm + i * 16 + l16) * 32 + quad * 8];
      bf[i] = *(const bf16x8*)&sB[(wn + i * 16 + l16) * 32 + quad * 8];
    }
#pragma unroll
    for (int i = 0; i < 4; ++i)
#pragma unroll
      for (int j = 0; j < 4; ++j)
        acc[i][j] = __builtin_amdgcn_mfma_f32_16x16x32_bf16(af[i], bf[j], acc[i][j], 0, 0, 0);
    __syncthreads();
  }

  // epilogue: C/D layout col=lane&15, row=quad*4+reg
#pragma unroll
  for (int i = 0; i < 4; ++i)
#pragma unroll
    for (int j = 0; j < 4; ++j)
#pragma unroll
      for (int r = 0; r < 4; ++r) {
        int row = tm + wm + i * 16 + quad * 4 + r;
        int col = tn + wn + j * 16 + l16;
        U[(size_t)row * NN + col] = f2bf(acc[i][j][r]);
      }
}

// ---------------- kernel 4: producer-consumer sequential scan --------------
// 256 blocks x 128 thr. Wave1 streams U (3 gate planes) + xb into dbuf LDS
// via global_load_lds(16B); wave0 computes the recurrence for 64 channels.
// Chunk = 32 L-steps = 16 KB; LDS = 2 x 16 KB. One wave-load = 2 steps:
// lanes [0..31]->step 2s, [32..63]->step 2s+1; within 32 lanes, 8-lane
// groups load the 128B segments {u0,u1,u2,x} (contiguous in global).
#define SCH 32                 /* steps per chunk   */
#define NCH (LL / SCH)         /* 64 chunks         */

__global__ __launch_bounds__(128, 1) void scan_kernel(const unsigned short* __restrict__ U,
                                                      const unsigned short* __restrict__ xb,
                                                      const float* __restrict__ wc,
                                                      const float* __restrict__ bias,
                                                      float* __restrict__ out) {
  __shared__ __align__(16) unsigned short lds[2][SCH * 256];  // 2 x 16 KB

  const int wv   = threadIdx.x >> 6;
  const int lane = threadIdx.x & 63;
  const int b  = blockIdx.x >> 3;              // 0..31
  const int d0 = (blockIdx.x & 7) << 6;        // 0,64,..,448

  if (wv == 1) {
    // ---------------- loader wave ----------------
    const int half = lane >> 5;                // which of the 2 steps
    const int r    = lane & 31;
    const int st   = r >> 3;                   // stream: 0,1,2 = gates, 3 = x
    const int idx  = r & 7;                    // 16B chunk within 128B segment
    const unsigned short* gp;
    size_t stride;                             // elements per L-step
    if (st < 3) { gp = U  + (size_t)b * NN + st * DD + d0 + idx * 8; stride = (size_t)BB * NN; }
    else        { gp = xb + (size_t)b * DD + d0 + idx * 8;           stride = (size_t)BB * DD; }
    gp += (size_t)half * stride;
    const size_t adv = stride * 2;             // per wave-load (2 steps)

    // prologue: chunk 0 into buf 0
#pragma unroll
    for (int s = 0; s < SCH / 2; ++s) { lds_cp16(&lds[0][s * 512], gp); gp += adv; }
    __syncthreads();
    for (int i = 0; i < NCH; ++i) {
      if (i + 1 < NCH) {
        unsigned short* lb = &lds[(i + 1) & 1][0];
#pragma unroll
        for (int s = 0; s < SCH / 2; ++s) { lds_cp16(&lb[s * 512], gp); gp += adv; }
      }
      __syncthreads();                         // compiler drains vmcnt first
    }
  } else {
    // ---------------- compute wave ----------------
    const int d = d0 + lane;
    const float kln = 1.442695040888963f;
    const float wcf = wc[d],      wcr = wc[DD + d];
    const float pf0 = -kln * bias[d],       pr0 = -kln * bias[DD + d];
    const float pf1 = -kln * wcf,           pr1 = -kln * wcr;
    float* hp = out + (size_t)b * DD + d;      // advance by B*D per step
    float c = 0.0f;

    __syncthreads();                           // matches loader prologue barrier
    for (int i = 0; i < NCH; ++i) {
      const unsigned short* lb = &lds[i & 1][0];
#pragma unroll
      for (int s = 0; s < SCH; ++s) {
        float u0 = bf2f(lb[s * 256 +       lane]);
        float u1 = bf2f(lb[s * 256 +  64 + lane]);
        float u2 = bf2f(lb[s * 256 + 128 + lane]);
        float xr = bf2f(lb[s * 256 + 192 + lane]);
        // fg = sigmoid(u1 + wcf*c + bf) computed as rcp(1 + exp2(-k*(...)))
        float tf = __builtin_fmaf(pf1, c, __builtin_fmaf(-kln, u1, pf0));
        float tr = __builtin_fmaf(pr1, c, __builtin_fmaf(-kln, u2, pr0));
        float fg = __builtin_amdgcn_rcpf(1.0f + __builtin_amdgcn_exp2f(tf));
        float rg = __builtin_amdgcn_rcpf(1.0f + __builtin_amdgcn_exp2f(tr));
        c = __builtin_fmaf(fg, c - u0, u0);
        *hp = __builtin_fmaf(rg, c - xr, xr);
        hp += BB * DD;
      }
      __syncthreads();
    }
    // c_last, concatenated after h
    out[(size_t)LL * BB * DD + (size_t)b * DD + d] = c;
  }
}

extern "C" void kernel_launch(void* const* d_in, const int* in_sizes, int n_in,
                              void* d_out, int out_size, void* d_ws, size_t ws_size,
                              hipStream_t stream) {
  const float* x    = (const float*)d_in[0];   // (L,B,D) fp32
  const float* W    = (const float*)d_in[1];   // (D,3D) fp32
  const float* wc   = (const float*)d_in[2];   // (2D,)  fp32
  const float* bias = (const float*)d_in[3];   // (2D,)  fp32
  float* out = (float*)d_out;                  // h (L,B,D) fp32 ++ c_last (B,D)

  // workspace layout (bf16): xb 64MB | WrT 1.5MB | U 192MB  (total ~258MB)
  unsigned short* xb = (unsigned short*)d_ws;
  unsigned short* Wt = xb + (size_t)MM * KK;
  unsigned short* U  = Wt + (size_t)NN * KK;

  cvt_x_kernel<<<(MM * KK) / (4 * 256), 256, 0, stream>>>(x, xb);
  cvt_w_kernel<<<(NN * KK) / 256, 256, 0, stream>>>(W, Wt);
  gemm_kernel<<<dim3(NN / 128, MM / 128), 256, 0, stream>>>(xb, Wt, U);
  scan_kernel<<<(BB * DD) / 64, 128, 0, stream>>>(U, xb, wc, bias, out);
}

// Round 3
// 458.714 us; speedup vs baseline: 1.7068x; 1.0273x over previous
//
#include <hip/hip_runtime.h>

// Problem constants (fixed by reference): L=2048, B=32, D=512
#define LL 2048
#define BB 32
#define DD 512
#define MM (LL * BB)   /* 65536 GEMM rows  */
#define NN (3 * DD)    /* 1536  GEMM cols  */
#define KK (DD)        /* 512   GEMM depth */

typedef short bf16x8 __attribute__((ext_vector_type(8)));
typedef float f32x4 __attribute__((ext_vector_type(4)));

__device__ __forceinline__ unsigned short f2bf(float f) {
  unsigned u = __builtin_bit_cast(unsigned, f);
  u += 0x7fffu + ((u >> 16) & 1u);   // round-to-nearest-even
  return (unsigned short)(u >> 16);
}
__device__ __forceinline__ float bf2f(unsigned short h) {
  unsigned u = (unsigned)h << 16;
  return __builtin_bit_cast(float, u);
}
// async global->LDS, 16B/lane; LDS dest = wave-uniform base + lane*16
__device__ __forceinline__ void lds_cp16(unsigned short* lds, const unsigned short* g) {
  __builtin_amdgcn_global_load_lds(
      (const __attribute__((address_space(1))) void*)g,
      (__attribute__((address_space(3))) void*)lds, 16, 0, 0);
}

// -------- kernel 1: x (L,B,D fp32) -> xb (B,L,D bf16), 4 elems/thread ------
// Permuted so GEMM row m = b*L + l: a C-fragment's 4 consecutive rows are
// then 4 consecutive timesteps of one batch (enables [M/4][N][4] U layout).
__global__ __launch_bounds__(256) void cvt_x_kernel(const float* __restrict__ x,
                                                    unsigned short* __restrict__ xb) {
  int i = blockIdx.x * 256 + threadIdx.x;      // 8388608 threads, exact
  int l   = i >> 12;                           // B*D/4 = 4096 float4 per l
  int rem = i & 4095;
  int b   = rem >> 7;                          // D/4 = 128 float4 per (l,b)
  int dg  = rem & 127;
  float4 v = ((const float4*)x)[i];
  ushort4 o;
  o.x = f2bf(v.x); o.y = f2bf(v.y); o.z = f2bf(v.z); o.w = f2bf(v.w);
  ((ushort4*)xb)[((size_t)b * LL + l) * 128 + dg] = o;
}

// ------- kernel 2: W (D x 3D fp32) -> WrT (bf16, [o'=g*D+d][k] N-major) ----
__global__ __launch_bounds__(256) void cvt_w_kernel(const float* __restrict__ W,
                                                    unsigned short* __restrict__ Wt) {
  int j = blockIdx.x * 256 + threadIdx.x;      // 786432 threads, exact
  int i  = j & (KK - 1);                       // k index 0..511
  int op = j >> 9;                             // o' 0..1535
  int g  = op >> 9;                            // gate 0..2
  int dd = op & (DD - 1);                      // d 0..511
  Wt[j] = f2bf(W[(size_t)i * NN + dd * 3 + g]);
}

// ---------------- kernel 3: GEMM  U'[M/4][N][4] (bf16) = xb * WrT^T --------
// m97 structure + (a) XOR-swizzled LDS (2-way max -> free), (b) full-line
// epilogue stores (kills RFO fetches), (c) XCD-aware block mapping.
__global__ __launch_bounds__(256) void gemm_kernel(const unsigned short* __restrict__ A,
                                                   const unsigned short* __restrict__ Bt,
                                                   unsigned short* __restrict__ U) {
  __shared__ __align__(16) unsigned short sA[128 * 32];
  __shared__ __align__(16) unsigned short sB[128 * 32];
  // XCD-aware mapping: xcd = n&7 owns M-tiles [xcd*64, xcd*64+64), N fastest.
  const int n   = blockIdx.x;                  // 6144 blocks
  const int xcd = n & 7;
  const int i2  = n >> 3;                      // 768 per xcd = 64 Mt x 12 Nt
  const int mt  = xcd * 64 + i2 / 12;
  const int nt  = i2 % 12;
  const int tm = mt * 128, tn = nt * 128;
  const int lane = threadIdx.x & 63;
  const int wv   = threadIdx.x >> 6;
  const int wm = (wv & 1) * 64;                // wave quadrant
  const int wn = (wv >> 1) * 64;
  const int quad = lane >> 4;                  // 0..3
  const int l16  = lane & 15;

  f32x4 acc[4][4] = {};

  const int srow = lane >> 2;                  // staging row within 16-row seg
  // swizzled source column-group: phys group (lane&3) holds logical group
  // (lane&3)^((row>>1)&3); row within seg = lane>>2 so (row>>1)&3=(lane>>3)&3
  const int scol = (((lane & 3) ^ ((lane >> 3) & 3))) * 8;
  // read-side: logical group `quad` of row (..+l16) lives at phys group
  // quad^((l16>>1)&3)
  const int aoff = (wm + l16) * 32 + ((quad ^ ((l16 >> 1) & 3)) * 8);
  const int boff = (wn + l16) * 32 + ((quad ^ ((l16 >> 1) & 3)) * 8);

  for (int k0 = 0; k0 < KK; k0 += 32) {
#pragma unroll
    for (int t = 0; t < 2; ++t) {
      int seg = wv * 2 + t;                    // 0..7, wave-uniform
      int row = seg * 16 + srow;
      lds_cp16(&sA[seg * 512], &A [(size_t)(tm + row) * KK + k0 + scol]);
      lds_cp16(&sB[seg * 512], &Bt[(size_t)(tn + row) * KK + k0 + scol]);
    }
    __syncthreads();                           // compiler drains vmcnt here

    bf16x8 af[4], bf[4];
#pragma unroll
    for (int i = 0; i < 4; ++i) {
      af[i] = *(const bf16x8*)&sA[aoff + i * 512];
      bf[i] = *(const bf16x8*)&sB[boff + i * 512];
    }
#pragma unroll
    for (int i = 0; i < 4; ++i)
#pragma unroll
      for (int j = 0; j < 4; ++j)
        acc[i][j] = __builtin_amdgcn_mfma_f32_16x16x32_bf16(af[i], bf[j], acc[i][j], 0, 0, 0);
    __syncthreads();
  }

  // epilogue: C/D layout col=lane&15, row=quad*4+r. Lane's 4 r-values are 4
  // consecutive rows -> pack as ushort4 into U'[rb][col][4]; one store inst
  // covers 4 full 128-B lines (16 lanes x 8 B contiguous per quad).
#pragma unroll
  for (int i = 0; i < 4; ++i) {
    size_t rb = (size_t)((tm + wm + i * 16) >> 2) + quad;
#pragma unroll
    for (int j = 0; j < 4; ++j) {
      int col = tn + wn + j * 16 + l16;
      ushort4 o;
      o.x = f2bf(acc[i][j][0]); o.y = f2bf(acc[i][j][1]);
      o.z = f2bf(acc[i][j][2]); o.w = f2bf(acc[i][j][3]);
      *(ushort4*)&U[(rb * NN + col) * 4] = o;
    }
  }
}

// ---------------- kernel 4: producer-consumer sequential scan --------------
// 256 blocks x 128 thr. Wave1 streams U' (3 gates) + xb into dbuf LDS via
// global_load_lds(16B); wave0 computes 64 channels of batch b.
// Chunk = 32 L-steps: U part = [gate][lblock][64ch x 4l] (12 KB, 24 segs of
// 512 B), x part = [step][64ch] (4 KB). lblock = l/4 matches U' packing.
#define SCH 32                 /* steps per chunk   */
#define NCH (LL / SCH)         /* 64 chunks         */

__global__ __launch_bounds__(128, 1) void scan_kernel(const unsigned short* __restrict__ U,
                                                      const unsigned short* __restrict__ xb,
                                                      const float* __restrict__ wc,
                                                      const float* __restrict__ bias,
                                                      float* __restrict__ out) {
  __shared__ __align__(16) unsigned short lds[2][SCH * 256];  // 2 x 16 KB

  const int wv   = threadIdx.x >> 6;
  const int lane = threadIdx.x & 63;
  const int b  = blockIdx.x >> 3;              // 0..31
  const int d0 = (blockIdx.x & 7) << 6;        // 0,64,..,448

  if (wv == 1) {
    // ---------------- loader wave ----------------
    const int h   = lane >> 5;                 // U: which of 2 segs per load
    const int c16 = lane & 31;                 // U: 16B chunk within 512B seg
    const int xs  = lane >> 3;                 // x: step within 8
    const int xc  = lane & 7;                  // x: 16B chunk within 128B

#define LOAD_CHUNK(ch, buf)                                                  \
    do {                                                                     \
      unsigned short* lb_ = &lds[buf][0];                                    \
      _Pragma("unroll") for (int w = 0; w < 12; ++w) {                       \
        int q  = 2 * w + h;          /* 0..23 = g*8 + lblock */              \
        int g  = q >> 3;                                                     \
        int lb2 = q & 7;                                                     \
        const unsigned short* gp =                                           \
            U + ((size_t)(b * 512 + (ch) * 8 + lb2) * NN + g * DD + d0) * 4  \
              + c16 * 8;                                                     \
        lds_cp16(lb_ + w * 512, gp);                                         \
      }                                                                      \
      _Pragma("unroll") for (int v = 0; v < 4; ++v) {                        \
        int s = v * 8 + xs;                                                  \
        const unsigned short* gp =                                           \
            xb + ((size_t)(b * LL + (ch) * 32 + s)) * DD + d0 + xc * 8;      \
        lds_cp16(lb_ + 6144 + v * 512, gp);                                  \
      }                                                                      \
    } while (0)

    LOAD_CHUNK(0, 0);
    __syncthreads();
    for (int i = 0; i < NCH; ++i) {
      if (i + 1 < NCH) LOAD_CHUNK(i + 1, (i + 1) & 1);
      __syncthreads();                         // compiler drains vmcnt first
    }
#undef LOAD_CHUNK
  } else {
    // ---------------- compute wave ----------------
    const int d = d0 + lane;
    const float kln = 1.442695040888963f;
    const float wcf = wc[d],      wcr = wc[DD + d];
    const float pf0 = -kln * bias[d],       pr0 = -kln * bias[DD + d];
    const float pf1 = -kln * wcf,           pr1 = -kln * wcr;
    float* hp = out + (size_t)b * DD + d;      // h[l][b][d], +B*D per step
    float c = 0.0f;

    __syncthreads();                           // matches loader prologue barrier
    for (int i = 0; i < NCH; ++i) {
      const unsigned short* lb_ = &lds[i & 1][0];
#pragma unroll
      for (int blk = 0; blk < 8; ++blk) {
        ushort4 U0 = *(const ushort4*)&lb_[       blk * 256 + lane * 4];
        ushort4 U1 = *(const ushort4*)&lb_[2048 + blk * 256 + lane * 4];
        ushort4 U2 = *(const ushort4*)&lb_[4096 + blk * 256 + lane * 4];
        const unsigned short* u0p = (const unsigned short*)&U0;
        const unsigned short* u1p = (const unsigned short*)&U1;
        const unsigned short* u2p = (const unsigned short*)&U2;
#pragma unroll
        for (int r = 0; r < 4; ++r) {
          int s = blk * 4 + r;
          float u0 = bf2f(u0p[r]);
          float u1 = bf2f(u1p[r]);
          float u2 = bf2f(u2p[r]);
          float xr = bf2f(lb_[6144 + s * 64 + lane]);
          // sigmoid(t) = rcp(1 + exp2(-k*t))
          float tf = __builtin_fmaf(pf1, c, __builtin_fmaf(-kln, u1, pf0));
          float tr = __builtin_fmaf(pr1, c, __builtin_fmaf(-kln, u2, pr0));
          float fg = __builtin_amdgcn_rcpf(1.0f + __builtin_amdgcn_exp2f(tf));
          float rg = __builtin_amdgcn_rcpf(1.0f + __builtin_amdgcn_exp2f(tr));
          c = __builtin_fmaf(fg, c - u0, u0);
          *hp = __builtin_fmaf(rg, c - xr, xr);
          hp += BB * DD;
        }
      }
      __syncthreads();
    }
    // c_last, concatenated after h
    out[(size_t)LL * BB * DD + (size_t)b * DD + d] = c;
  }
}

extern "C" void kernel_launch(void* const* d_in, const int* in_sizes, int n_in,
                              void* d_out, int out_size, void* d_ws, size_t ws_size,
                              hipStream_t stream) {
  const float* x    = (const float*)d_in[0];   // (L,B,D) fp32
  const float* W    = (const float*)d_in[1];   // (D,3D) fp32
  const float* wc   = (const float*)d_in[2];   // (2D,)  fp32
  const float* bias = (const float*)d_in[3];   // (2D,)  fp32
  float* out = (float*)d_out;                  // h (L,B,D) fp32 ++ c_last (B,D)

  // workspace layout (bf16): xb 64MB | WrT 1.5MB | U' 192MB  (total ~258MB)
  unsigned short* xb = (unsigned short*)d_ws;
  unsigned short* Wt = xb + (size_t)MM * KK;
  unsigned short* U  = Wt + (size_t)NN * KK;

  cvt_x_kernel<<<(MM * KK) / (4 * 256), 256, 0, stream>>>(x, xb);
  cvt_w_kernel<<<(NN * KK) / 256, 256, 0, stream>>>(W, Wt);
  gemm_kernel<<<(MM / 128) * (NN / 128), 256, 0, stream>>>(xb, Wt, U);
  scan_kernel<<<(BB * DD) / 64, 128, 0, stream>>>(U, xb, wc, bias, out);
}